// Round 3
// baseline (350.579 us; speedup 1.0000x reference)
//
#include <hip/hip_runtime.h>

typedef unsigned short ushort_t;
typedef unsigned int uint_t;
typedef __attribute__((ext_vector_type(8))) short short8;
typedef __attribute__((ext_vector_type(4))) float floatx4;

__device__ __forceinline__ ushort_t f2bf(float f) {
    union { float f; uint_t u; } c; c.f = f;
    uint_t u = c.u;
    return (ushort_t)((u + 0x7fffu + ((u >> 16) & 1u)) >> 16);  // RNE
}
__device__ __forceinline__ floatx4 mfma16x16(short8 a, short8 b, floatx4 c) {
    return __builtin_amdgcn_mfma_f32_16x16x32_bf16(a, b, c, 0, 0, 0);
}
__device__ __forceinline__ floatx4 zero4() { floatx4 z = {0.f, 0.f, 0.f, 0.f}; return z; }

// ---------------------------------------------------------------------------
// Fused convert+transpose: W[k][j] (1024x1024 f32) -> WT[j][k] bf16.
// blockIdx.y picks matrix {Wq,Wk,Wv,Wo}.
// ---------------------------------------------------------------------------
__global__ __launch_bounds__(256) void transpose_w(
    const float* __restrict__ W0, const float* __restrict__ W1,
    const float* __restrict__ W2, const float* __restrict__ W3,
    ushort_t* __restrict__ WT)
{
    __shared__ ushort_t tile[64][65];
    const float* W = (blockIdx.y == 0) ? W0 : (blockIdx.y == 1) ? W1
                   : (blockIdx.y == 2) ? W2 : W3;
    ushort_t* dst = WT + (size_t)blockIdx.y * (1024 * 1024);
    const int t = threadIdx.x;
    const int r = t >> 2, p = t & 3;
    const int j0 = (blockIdx.x & 15) << 6, k0 = (blockIdx.x >> 4) << 6;

    const float* src = W + (size_t)(k0 + r) * 1024 + j0 + p * 16;
    float4 f0 = *(const float4*)(src);
    float4 f1 = *(const float4*)(src + 4);
    float4 f2 = *(const float4*)(src + 8);
    float4 f3 = *(const float4*)(src + 12);
    ushort_t* tr = &tile[r][p * 16];
    tr[0] = f2bf(f0.x); tr[1] = f2bf(f0.y); tr[2]  = f2bf(f0.z); tr[3]  = f2bf(f0.w);
    tr[4] = f2bf(f1.x); tr[5] = f2bf(f1.y); tr[6]  = f2bf(f1.z); tr[7]  = f2bf(f1.w);
    tr[8] = f2bf(f2.x); tr[9] = f2bf(f2.y); tr[10] = f2bf(f2.z); tr[11] = f2bf(f2.w);
    tr[12] = f2bf(f3.x); tr[13] = f2bf(f3.y); tr[14] = f2bf(f3.z); tr[15] = f2bf(f3.w);
    __syncthreads();
    __align__(16) ushort_t buf[16];
#pragma unroll
    for (int i = 0; i < 16; ++i) buf[i] = tile[p * 16 + i][r];
    ushort_t* o = dst + (size_t)(j0 + r) * 1024 + k0 + p * 16;
    *(uint4*)(o)     = *(uint4*)(buf);
    *(uint4*)(o + 8) = *(uint4*)(buf + 8);
}

// ---------------------------------------------------------------------------
// GEMM: C[r][c] = sum_k A[r][k] * Bt[c][k] + bias[c].  M=4096, N=1024, K=1024.
// Bt is bf16 (pre-transposed weights). bias is f32.
// 128x128 tile, BK=32, 4 waves each computing 64x64 via 4x4 of 16x16x32 MFMA.
// MODE 0: A f32,  write bf16 to [B,H,S,dk]   (Q, K projections)
// MODE 1: A f32,  write bf16 to [B,H,dk,S]   (V projection, pre-transposed)
// MODE 2: A bf16, write f32 row-major [r][c] (final output)
// ---------------------------------------------------------------------------
template <int MODE>
__global__ __launch_bounds__(256) void gemm128(
    const void* __restrict__ Av, const ushort_t* __restrict__ Bt,
    const float* __restrict__ bias, void* __restrict__ Dstv)
{
    constexpr int Kdim = 1024;
    __shared__ __align__(16) ushort_t As[128 * 40];  // +8 pad: 2-way banks (free)
    __shared__ __align__(16) ushort_t Bs[128 * 40];
    const int tid = threadIdx.x;
    const int lane = tid & 63, wid = tid >> 6;
    const int quad = lane >> 4, l16 = lane & 15;
    const int wm = wid >> 1, wn = wid & 1;
    const int row0 = blockIdx.y << 7, col0 = blockIdx.x << 7;

    floatx4 acc[4][4];
#pragma unroll
    for (int i = 0; i < 4; ++i)
#pragma unroll
        for (int j = 0; j < 4; ++j) acc[i][j] = zero4();

    const int sr = tid >> 1, sh = tid & 1;  // staging: 2 threads/row, 16 elems each
    const float*    Agf = (const float*)Av    + (size_t)(row0 + sr) * Kdim + sh * 16;
    const ushort_t* Agh = (const ushort_t*)Av + (size_t)(row0 + sr) * Kdim + sh * 16;
    const ushort_t* Bg  = Bt + (size_t)(col0 + sr) * Kdim + sh * 16;
    ushort_t* Asw = As + sr * 40 + sh * 16;
    ushort_t* Bsw = Bs + sr * 40 + sh * 16;

    for (int k0 = 0; k0 < Kdim; k0 += 32) {
        __syncthreads();
        uint4 b0 = *(const uint4*)(Bg + k0);
        uint4 b1 = *(const uint4*)(Bg + k0 + 8);
        if (MODE == 2) {
            uint4 a0 = *(const uint4*)(Agh + k0);
            uint4 a1 = *(const uint4*)(Agh + k0 + 8);
            *(uint4*)Asw = a0; *(uint4*)(Asw + 8) = a1;
        } else {
            float4 f0 = *(const float4*)(Agf + k0);
            float4 f1 = *(const float4*)(Agf + k0 + 4);
            float4 f2 = *(const float4*)(Agf + k0 + 8);
            float4 f3 = *(const float4*)(Agf + k0 + 12);
            __align__(16) ushort_t t[16];
            t[0] = f2bf(f0.x); t[1] = f2bf(f0.y); t[2]  = f2bf(f0.z); t[3]  = f2bf(f0.w);
            t[4] = f2bf(f1.x); t[5] = f2bf(f1.y); t[6]  = f2bf(f1.z); t[7]  = f2bf(f1.w);
            t[8] = f2bf(f2.x); t[9] = f2bf(f2.y); t[10] = f2bf(f2.z); t[11] = f2bf(f2.w);
            t[12] = f2bf(f3.x); t[13] = f2bf(f3.y); t[14] = f2bf(f3.z); t[15] = f2bf(f3.w);
            *(uint4*)Asw = *(uint4*)t; *(uint4*)(Asw + 8) = *(uint4*)(t + 8);
        }
        *(uint4*)Bsw = b0; *(uint4*)(Bsw + 8) = b1;
        __syncthreads();

        short8 af[4], bfr[4];
#pragma unroll
        for (int i = 0; i < 4; ++i)
            af[i] = *(const short8*)(As + (wm * 64 + i * 16 + l16) * 40 + quad * 8);
#pragma unroll
        for (int j = 0; j < 4; ++j)
            bfr[j] = *(const short8*)(Bs + (wn * 64 + j * 16 + l16) * 40 + quad * 8);
#pragma unroll
        for (int i = 0; i < 4; ++i)
#pragma unroll
            for (int j = 0; j < 4; ++j)
                acc[i][j] = mfma16x16(af[i], bfr[j], acc[i][j]);
    }

#pragma unroll
    for (int i = 0; i < 4; ++i) {
#pragma unroll
        for (int j = 0; j < 4; ++j) {
            const int c = col0 + wn * 64 + j * 16 + l16;
            const float bv = bias[c];
#pragma unroll
            for (int rr = 0; rr < 4; ++rr) {
                const int r = row0 + wm * 64 + i * 16 + quad * 4 + rr;
                const float v = acc[i][j][rr] + bv;
                if (MODE == 0) {
                    const int b = r >> 11, s = r & 2047, h = c >> 6, d = c & 63;
                    ((ushort_t*)Dstv)[(((b * 16 + h) * 2048 + s) << 6) + d] = f2bf(v);
                } else if (MODE == 1) {
                    const int b = r >> 11, s = r & 2047, h = c >> 6, d = c & 63;
                    ((ushort_t*)Dstv)[(((b * 16 + h) * 64 + d) << 11) + s] = f2bf(v);
                } else {
                    ((float*)Dstv)[(size_t)r * 1024 + c] = v;
                }
            }
        }
    }
}

// ---------------------------------------------------------------------------
// Attention, fixed-shift softmax (NaN-proof): p = exp(clamp(s, +-60)).
// Exact softmax since scores are bounded (|s| <~ 2 for this distribution).
// Per (head, 64 q-rows) block: 4 waves x 16 q-rows. K tiles of 64.
// Q,K in [B,H,S,64] bf16; Vt in [B,H,64,S] bf16. Out -> [B,S,D] bf16.
// ---------------------------------------------------------------------------
__global__ __launch_bounds__(256) void attn64(
    const ushort_t* __restrict__ Q, const ushort_t* __restrict__ K,
    const ushort_t* __restrict__ Vt, ushort_t* __restrict__ Out)
{
    __shared__ __align__(16) ushort_t Ks[64 * 72];      // K tile  [kcol][d], pad 8
    __shared__ __align__(16) ushort_t Vs[64 * 72];      // V^T tile [d][kcol]
    __shared__ __align__(16) ushort_t Ps[4][16 * 72];   // per-wave P round-trip

    const int tid = threadIdx.x;
    const int lane = tid & 63, wid = tid >> 6;
    const int quad = lane >> 4, l16 = lane & 15;
    const int bh = blockIdx.y;        // b*16 + h
    const int q0 = blockIdx.x << 6;

    const ushort_t* Qh = Q + (size_t)bh * (2048 * 64);
    const ushort_t* Kh = K + (size_t)bh * (2048 * 64);
    const ushort_t* Vh = Vt + (size_t)bh * (64 * 2048);

    // Q A-fragments (held in registers for the whole block)
    const int qr = q0 + wid * 16 + l16;
    const short8 qf0 = *(const short8*)(Qh + qr * 64 + quad * 8);
    const short8 qf1 = *(const short8*)(Qh + qr * 64 + 32 + quad * 8);

    float l_st[4];
    floatx4 o_acc[4];
#pragma unroll
    for (int r = 0; r < 4; ++r) { l_st[r] = 0.f; o_acc[r] = zero4(); }

    const int sr = tid >> 2, sp = tid & 3;  // staging: 4 threads/row, 16 elems each
    const float rs = 0.02209708691f;        // 1/sqrt(2048)  (quirk: sqrt(S) not sqrt(dk))

    for (int kt = 0; kt < 2048; kt += 64) {
        __syncthreads();
        {
            const ushort_t* src = Kh + (kt + sr) * 64 + sp * 16;
            uint4 v0 = *(const uint4*)src;
            uint4 v1 = *(const uint4*)(src + 8);
            *(uint4*)(Ks + sr * 72 + sp * 16) = v0;
            *(uint4*)(Ks + sr * 72 + sp * 16 + 8) = v1;
            const ushort_t* vsrc = Vh + sr * 2048 + kt + sp * 16;
            uint4 w0 = *(const uint4*)vsrc;
            uint4 w1 = *(const uint4*)(vsrc + 8);
            *(uint4*)(Vs + sr * 72 + sp * 16) = w0;
            *(uint4*)(Vs + sr * 72 + sp * 16 + 8) = w1;
        }
        __syncthreads();

        // S = Q K^T for this tile: 16 q-rows x 64 k-cols per wave
        floatx4 sa[4];
#pragma unroll
        for (int g = 0; g < 4; ++g) {
            sa[g] = zero4();
            const short8 kf0 = *(const short8*)(Ks + (g * 16 + l16) * 72 + quad * 8);
            const short8 kf1 = *(const short8*)(Ks + (g * 16 + l16) * 72 + 32 + quad * 8);
            sa[g] = mfma16x16(qf0, kf0, sa[g]);
            sa[g] = mfma16x16(qf1, kf1, sa[g]);
        }

        // p = exp(clamp(s)): C-layout row = quad*4+r, col = g*16+l16
        ushort_t* pw = &Ps[wid][0];
#pragma unroll
        for (int g = 0; g < 4; ++g)
#pragma unroll
            for (int r = 0; r < 4; ++r) {
                float s = sa[g][r] * rs;
                s = fminf(fmaxf(s, -60.f), 60.f);
                const float p = __expf(s);
                l_st[r] += p;
                pw[(quad * 4 + r) * 72 + g * 16 + l16] = f2bf(p);
            }

        // P (C-layout) -> A-layout via per-wave LDS round trip.
        __syncthreads();
        const short8 pf0 = *(const short8*)(pw + l16 * 72 + quad * 8);
        const short8 pf1 = *(const short8*)(pw + l16 * 72 + 32 + quad * 8);
#pragma unroll
        for (int g = 0; g < 4; ++g) {
            const short8 vf0 = *(const short8*)(Vs + (g * 16 + l16) * 72 + quad * 8);
            const short8 vf1 = *(const short8*)(Vs + (g * 16 + l16) * 72 + 32 + quad * 8);
            o_acc[g] = mfma16x16(pf0, vf0, o_acc[g]);
            o_acc[g] = mfma16x16(pf1, vf1, o_acc[g]);
        }
    }

    // Reduce denominator across the 16 lanes holding each row's columns.
#pragma unroll
    for (int r = 0; r < 4; ++r) {
        l_st[r] += __shfl_xor(l_st[r], 1);
        l_st[r] += __shfl_xor(l_st[r], 2);
        l_st[r] += __shfl_xor(l_st[r], 4);
        l_st[r] += __shfl_xor(l_st[r], 8);
    }

    const int b = bh >> 4, h = bh & 15;
    const int s0 = q0 + wid * 16 + quad * 4;
#pragma unroll
    for (int g = 0; g < 4; ++g)
#pragma unroll
        for (int r = 0; r < 4; ++r) {
            const float v = o_acc[g][r] / l_st[r];
            Out[(size_t)(b * 2048 + s0 + r) * 1024 + h * 64 + g * 16 + l16] = f2bf(v);
        }
}

// ---------------------------------------------------------------------------
// Launch. Inputs f32 (per reference dtypes); output f32.
// ws layout (bytes):
//   [0,8M)    WT: Wq^T,Wk^T,Wv^T,Wo^T (1M bf16 elems each)
//   [8M,16M)  Q  [B,H,S,64] bf16
//   [16M,24M) K  [B,H,S,64] bf16
//   [24M,32M) V^T[B,H,64,S] bf16
//   [32M,40M) attn context [B,S,D] bf16
// Total 40 MiB.
// ---------------------------------------------------------------------------
extern "C" void kernel_launch(void* const* d_in, const int* in_sizes, int n_in,
                              void* d_out, int out_size, void* d_ws, size_t ws_size,
                              hipStream_t stream) {
    const float* queries = (const float*)d_in[0];
    const float* keys    = (const float*)d_in[1];
    const float* values  = (const float*)d_in[2];
    const float* Wq = (const float*)d_in[3];
    const float* bq = (const float*)d_in[4];
    const float* Wk = (const float*)d_in[5];
    const float* bk = (const float*)d_in[6];
    const float* Wv = (const float*)d_in[7];
    const float* bv = (const float*)d_in[8];
    const float* Wo = (const float*)d_in[9];
    const float* bo = (const float*)d_in[10];

    char* ws = (char*)d_ws;
    const size_t MB = 1024 * 1024;
    ushort_t* WT  = (ushort_t*)(ws);
    ushort_t* Qp  = (ushort_t*)(ws + 8 * MB);
    ushort_t* Kp  = (ushort_t*)(ws + 16 * MB);
    ushort_t* Vtp = (ushort_t*)(ws + 24 * MB);
    ushort_t* An  = (ushort_t*)(ws + 32 * MB);

    dim3 tb(256);
    transpose_w<<<dim3(256, 4), tb, 0, stream>>>(Wq, Wk, Wv, Wo, WT);
    gemm128<0><<<dim3(8, 32), tb, 0, stream>>>(queries, WT, bq, Qp);
    gemm128<0><<<dim3(8, 32), tb, 0, stream>>>(keys, WT + 1048576, bk, Kp);
    gemm128<1><<<dim3(8, 32), tb, 0, stream>>>(values, WT + 2097152, bv, Vtp);
    attn64<<<dim3(32, 32), tb, 0, stream>>>(Qp, Kp, Vtp, An);
    gemm128<2><<<dim3(8, 32), tb, 0, stream>>>(An, WT + 3145728, bo, d_out);
}

// Round 6
// 263.378 us; speedup vs baseline: 1.3311x; 1.3311x over previous
//
#include <hip/hip_runtime.h>

typedef unsigned short ushort_t;
typedef unsigned int uint_t;
typedef __attribute__((ext_vector_type(8))) short short8;
typedef __attribute__((ext_vector_type(4))) float floatx4;

#define QSCALE 0.03187936f  // (1/sqrt(2048)) * log2(e): quirk scale + exp2 fold

__device__ __forceinline__ ushort_t f2bf(float f) {
    union { float f; uint_t u; } c; c.f = f;
    uint_t u = c.u;
    return (ushort_t)((u + 0x7fffu + ((u >> 16) & 1u)) >> 16);  // RNE
}
__device__ __forceinline__ floatx4 mfma16x32(short8 a, short8 b, floatx4 c) {
    return __builtin_amdgcn_mfma_f32_16x16x32_bf16(a, b, c, 0, 0, 0);
}
__device__ __forceinline__ floatx4 zero4() { floatx4 z = {0.f, 0.f, 0.f, 0.f}; return z; }

// Async 16B global->LDS. Pass the PER-LANE lds pointer (base + lane*16B slot):
// HW takes lane0's pointer as the wave base and strides lane*16 itself, which
// matches our linear slot mapping exactly.
__device__ __forceinline__ void gload16(const ushort_t* g, ushort_t* l) {
    __builtin_amdgcn_global_load_lds(
        (const __attribute__((address_space(1))) void*)g,
        (__attribute__((address_space(3))) void*)l, 16, 0, 0);
}

// ---------------------------------------------------------------------------
// f32 -> bf16 convert (RNE), 8 elems/thread. n = 4194304 -> grid 2048 x 256.
// ---------------------------------------------------------------------------
__global__ __launch_bounds__(256) void cvt_bf16(
    const float* __restrict__ src, ushort_t* __restrict__ dst)
{
    const int i = (blockIdx.x * 256 + threadIdx.x) * 8;
    float4 f0 = *(const float4*)(src + i);
    float4 f1 = *(const float4*)(src + i + 4);
    __align__(16) ushort_t t[8];
    t[0] = f2bf(f0.x); t[1] = f2bf(f0.y); t[2] = f2bf(f0.z); t[3] = f2bf(f0.w);
    t[4] = f2bf(f1.x); t[5] = f2bf(f1.y); t[6] = f2bf(f1.z); t[7] = f2bf(f1.w);
    *(uint4*)(dst + i) = *(uint4*)t;
}

// ---------------------------------------------------------------------------
// Fused convert+transpose: W[k][j] (1024x1024 f32) -> WT[j][k] bf16.
// ---------------------------------------------------------------------------
__global__ __launch_bounds__(256) void transpose_w(
    const float* __restrict__ W0, const float* __restrict__ W1,
    const float* __restrict__ W2, const float* __restrict__ W3,
    ushort_t* __restrict__ WT)
{
    __shared__ ushort_t tile[64][65];
    const float* W = (blockIdx.y == 0) ? W0 : (blockIdx.y == 1) ? W1
                   : (blockIdx.y == 2) ? W2 : W3;
    ushort_t* dst = WT + (size_t)blockIdx.y * (1024 * 1024);
    const int t = threadIdx.x;
    const int r = t >> 2, p = t & 3;
    const int j0 = (blockIdx.x & 15) << 6, k0 = (blockIdx.x >> 4) << 6;

    const float* src = W + (size_t)(k0 + r) * 1024 + j0 + p * 16;
    float4 f0 = *(const float4*)(src);
    float4 f1 = *(const float4*)(src + 4);
    float4 f2 = *(const float4*)(src + 8);
    float4 f3 = *(const float4*)(src + 12);
    ushort_t* tr = &tile[r][p * 16];
    tr[0] = f2bf(f0.x); tr[1] = f2bf(f0.y); tr[2]  = f2bf(f0.z); tr[3]  = f2bf(f0.w);
    tr[4] = f2bf(f1.x); tr[5] = f2bf(f1.y); tr[6]  = f2bf(f1.z); tr[7]  = f2bf(f1.w);
    tr[8] = f2bf(f2.x); tr[9] = f2bf(f2.y); tr[10] = f2bf(f2.z); tr[11] = f2bf(f2.w);
    tr[12] = f2bf(f3.x); tr[13] = f2bf(f3.y); tr[14] = f2bf(f3.z); tr[15] = f2bf(f3.w);
    __syncthreads();
    __align__(16) ushort_t buf[16];
#pragma unroll
    for (int i = 0; i < 16; ++i) buf[i] = tile[p * 16 + i][r];
    ushort_t* o = dst + (size_t)(j0 + r) * 1024 + k0 + p * 16;
    *(uint4*)(o)     = *(uint4*)(buf);
    *(uint4*)(o + 8) = *(uint4*)(buf + 8);
}

// ---------------------------------------------------------------------------
// GEMM: C[r][c] = sum_k A[r][k]*WT[c][k] + bias[c].  M=4096,N=1024,K=1024, all bf16.
// 128x128 tile, BK=32, global_load_lds(16B) staging, XOR-swizzled LDS chunks.
// mode = blockIdx.z + zbase:
//   0: Q proj -> bf16 [B,H,S,64], scaled by QSCALE
//   1: K proj -> bf16 [B,H,S,64]
//   2: V proj -> bf16 [B,H,64,S]
//   3: out    -> f32  [r][c]
// ---------------------------------------------------------------------------
__global__ __launch_bounds__(256) void gemm_bt(
    const ushort_t* __restrict__ A0, const ushort_t* __restrict__ A1,
    const ushort_t* __restrict__ A2, const ushort_t* __restrict__ A3,
    const ushort_t* __restrict__ WT,
    const float* __restrict__ b0, const float* __restrict__ b1,
    const float* __restrict__ b2, const float* __restrict__ b3,
    ushort_t* __restrict__ Dq, ushort_t* __restrict__ Dk,
    ushort_t* __restrict__ Dv, float* __restrict__ Dout, int zbase)
{
    __shared__ __align__(16) ushort_t As[128 * 32];  // no pad: global_load_lds layout
    __shared__ __align__(16) ushort_t Bs[128 * 32];

    const int mode = blockIdx.z + zbase;
    const ushort_t* A = (mode == 0) ? A0 : (mode == 1) ? A1 : (mode == 2) ? A2 : A3;
    const float* bias = (mode == 0) ? b0 : (mode == 1) ? b1 : (mode == 2) ? b2 : b3;
    const ushort_t* Bt = WT + (size_t)mode * 1048576;

    const int tid = threadIdx.x;
    const int lane = tid & 63, wid = tid >> 6;
    const int quad = lane >> 4, l16 = lane & 15;
    const int wm = wid >> 1, wn = wid & 1;
    const int row0 = blockIdx.y << 7, col0 = blockIdx.x << 7;

    floatx4 acc[4][4];
#pragma unroll
    for (int i = 0; i < 4; ++i)
#pragma unroll
        for (int j = 0; j < 4; ++j) acc[i][j] = zero4();

    // staging: tile 128 rows x 32 k = 8KB = 512 chunks(16B); 2 rounds x 256 thr.
    // slot s holds global chunk s^(row&3)  (XOR swizzle, conflict-free frag reads)
    const int i0 = tid, i1 = 256 + tid;
    const int r0_ = i0 >> 2, c0_ = (i0 & 3) ^ (r0_ & 3);
    const int r1_ = i1 >> 2, c1_ = (i1 & 3) ^ (r1_ & 3);
    const ushort_t* gA0 = A  + (size_t)(row0 + r0_) * 1024 + c0_ * 8;
    const ushort_t* gA1 = A  + (size_t)(row0 + r1_) * 1024 + c1_ * 8;
    const ushort_t* gB0 = Bt + (size_t)(col0 + r0_) * 1024 + c0_ * 8;
    const ushort_t* gB1 = Bt + (size_t)(col0 + r1_) * 1024 + c1_ * 8;
    ushort_t* lA0 = As + i0 * 8;  ushort_t* lA1 = As + i1 * 8;
    ushort_t* lB0 = Bs + i0 * 8;  ushort_t* lB1 = Bs + i1 * 8;

    // fragment read offsets (shorts): row*32 + (quad ^ (row&3))*8
    const int ra = wm * 64 + l16, rb = wn * 64 + l16;   // + i*16 keeps row&3
    const int sa_off = (quad ^ (l16 & 3)) * 8;

    for (int k0 = 0; k0 < 1024; k0 += 32) {
        __syncthreads();
        gload16(gA0 + k0, lA0);
        gload16(gA1 + k0, lA1);
        gload16(gB0 + k0, lB0);
        gload16(gB1 + k0, lB1);
        __syncthreads();

        short8 af[4], bf[4];
#pragma unroll
        for (int i = 0; i < 4; ++i)
            af[i] = *(const short8*)(As + (ra + i * 16) * 32 + sa_off);
#pragma unroll
        for (int j = 0; j < 4; ++j)
            bf[j] = *(const short8*)(Bs + (rb + j * 16) * 32 + sa_off);
#pragma unroll
        for (int i = 0; i < 4; ++i)
#pragma unroll
            for (int j = 0; j < 4; ++j)
                acc[i][j] = mfma16x32(af[i], bf[j], acc[i][j]);
    }

    const float sc = (mode == 0) ? QSCALE : 1.f;
#pragma unroll
    for (int i = 0; i < 4; ++i) {
#pragma unroll
        for (int j = 0; j < 4; ++j) {
            const int c = col0 + wn * 64 + j * 16 + l16;
            const float bv = bias[c];
#pragma unroll
            for (int rr = 0; rr < 4; ++rr) {
                const int r = row0 + wm * 64 + i * 16 + quad * 4 + rr;
                const float v = (acc[i][j][rr] + bv) * sc;
                if (mode <= 1) {
                    const int b = r >> 11, s = r & 2047, h = c >> 6, d = c & 63;
                    ushort_t* D = (mode == 0) ? Dq : Dk;
                    D[(((b * 16 + h) * 2048 + s) << 6) + d] = f2bf(v);
                } else if (mode == 2) {
                    const int b = r >> 11, s = r & 2047, h = c >> 6, d = c & 63;
                    Dv[(((b * 16 + h) * 64 + d) << 11) + s] = f2bf(v);
                } else {
                    Dout[(size_t)r * 1024 + c] = v;
                }
            }
        }
    }
}

// ---------------------------------------------------------------------------
// Attention via S^T trick. Per block: (head bh, 64 q-rows), 4 waves x 16 rows.
// S^T = K·Q^T (swapped MFMA operands) -> C-layout row=kcol(quad*4+r),
// col=qrow(l16). That IS the A-operand lane ownership needed for PV: lane
// (l16,quad) holds P[qrow=l16][kcol=quad*4+r]. PV uses the K=32 MFMA with
// ZERO-PADDED operands: semantic kcol'=4q+r placed at physical k=8q+r
// (slots j=0..3), zeros j=4..7, identically on A (P) and B (V) — the
// contraction then computes exactly sum_{q,r} P[m][4q+r]*V[4q+r][n].
// Fixed-shift softmax: p=exp2(min(s,80)) (scale+log2e folded into Q),
// p truncated to bf16, denominator summed over truncated values
// (self-normalizing). K/V staged via global_load_lds with XOR swizzle.
// ---------------------------------------------------------------------------
__global__ __launch_bounds__(256) void attn64(
    const ushort_t* __restrict__ Q, const ushort_t* __restrict__ K,
    const ushort_t* __restrict__ Vt, ushort_t* __restrict__ Out)
{
    __shared__ __align__(16) ushort_t Ks[64 * 64];  // [kcol][d], swizzled chunks
    __shared__ __align__(16) ushort_t Vs[64 * 64];  // [d][kcol], swizzled chunks

    const int tid = threadIdx.x;
    const int lane = tid & 63, wid = tid >> 6;
    const int quad = lane >> 4, l16 = lane & 15;
    const int bh = blockIdx.y;
    const int q0 = blockIdx.x << 6;

    const ushort_t* Qh = Q + (size_t)bh * (2048 * 64);
    const ushort_t* Kh = K + (size_t)bh * (2048 * 64);
    const ushort_t* Vh = Vt + (size_t)bh * (64 * 2048);

    // Q B-fragments: B[n=qrow=l16][k=d=quad*8+j]
    const int qr = q0 + wid * 16 + l16;
    const short8 qf0 = *(const short8*)(Qh + (size_t)qr * 64 + quad * 8);
    const short8 qf1 = *(const short8*)(Qh + (size_t)qr * 64 + 32 + quad * 8);

    float l_st = 0.f;
    floatx4 o_acc[4];
#pragma unroll
    for (int d = 0; d < 4; ++d) o_acc[d] = zero4();

    // staging: 64 rows x 128B = 8 chunks/row; 2 rounds x 256 threads per matrix
    const int i0 = tid, i1 = 256 + tid;
    const int kr0 = i0 >> 3, kc0 = (i0 & 7) ^ (kr0 & 7);
    const int kr1 = i1 >> 3, kc1 = (i1 & 7) ^ (kr1 & 7);
    const ushort_t* gK0 = Kh + (size_t)kr0 * 64 + kc0 * 8;
    const ushort_t* gK1 = Kh + (size_t)kr1 * 64 + kc1 * 8;
    const ushort_t* gV0 = Vh + (size_t)kr0 * 2048 + kc0 * 8;
    const ushort_t* gV1 = Vh + (size_t)kr1 * 2048 + kc1 * 8;
    ushort_t* lK0 = Ks + i0 * 8;  ushort_t* lK1 = Ks + i1 * 8;
    ushort_t* lV0 = Vs + i0 * 8;  ushort_t* lV1 = Vs + i1 * 8;

    const int l7 = l16 & 7;

    for (int kt = 0; kt < 2048; kt += 64) {
        __syncthreads();
        gload16(gK0 + (size_t)kt * 64, lK0);
        gload16(gK1 + (size_t)kt * 64, lK1);
        gload16(gV0 + kt, lV0);
        gload16(gV1 + kt, lV1);
        __syncthreads();

        // S^T tiles: A = K-frag (m=kcol), B = Q-frag (n=qrow)
        floatx4 sa[4];
#pragma unroll
        for (int g = 0; g < 4; ++g) {
            const int row = g * 16 + l16;  // kcol
            const short8 kf0 = *(const short8*)(Ks + row * 64 + ((quad ^ l7) * 8));
            const short8 kf1 = *(const short8*)(Ks + row * 64 + (((quad + 4) ^ l7) * 8));
            sa[g] = mfma16x32(kf0, qf0, zero4());
            sa[g] = mfma16x32(kf1, qf1, sa[g]);
        }

        // softmax + pack; lane's 16 scores all belong to qrow=l16
#pragma unroll
        for (int g = 0; g < 4; ++g) {
            uint_t ub[4];
#pragma unroll
            for (int r = 0; r < 4; ++r) {
                const float e = __builtin_amdgcn_exp2f(fminf(sa[g][r], 80.f));
                const uint_t u = __float_as_uint(e) & 0xffff0000u;
                l_st += __uint_as_float(u);   // sum the TRUNCATED value
                ub[r] = u;
            }
            union { uint_t u[4]; short8 s; } pc;
            pc.u[0] = (ub[0] >> 16) | ub[1];
            pc.u[1] = (ub[2] >> 16) | ub[3];
            pc.u[2] = 0u; pc.u[3] = 0u;     // zero-pad k slots 4..7
            const short8 pf = pc.s;

            // PV: o[qrow][d] += P x V^T over this g-block (16 kcols)
#pragma unroll
            for (int db = 0; db < 4; ++db) {
                const int vrow = db * 16 + l16;  // d
                const int ch = g * 2 + (quad >> 1);
                const ushort_t* vp =
                    Vs + vrow * 64 + ((ch ^ (l16 & 7)) * 8) + (quad & 1) * 4;
                union { uint_t u[4]; short8 s; } vc;
                vc.u[0] = *(const uint_t*)(vp);
                vc.u[1] = *(const uint_t*)(vp + 2);
                vc.u[2] = 0u; vc.u[3] = 0u;  // zero-pad k slots 4..7
                o_acc[db] = mfma16x32(pf, vc.s, o_acc[db]);
            }
        }
    }

    // denominator: sum across the 4 quads sharing qrow=l16, then broadcast
    l_st += __shfl_xor(l_st, 16);
    l_st += __shfl_xor(l_st, 32);

    const int b = bh >> 4, h = bh & 15;
    const int s0 = q0 + wid * 16 + quad * 4;
#pragma unroll
    for (int r = 0; r < 4; ++r) {
        const float lr = __shfl(l_st, quad * 4 + r);  // l of qrow quad*4+r
        const float inv = 1.f / lr;
#pragma unroll
        for (int db = 0; db < 4; ++db) {
            const float v = o_acc[db][r] * inv;
            Out[(size_t)(b * 2048 + s0 + r) * 1024 + h * 64 + db * 16 + l16] = f2bf(v);
        }
    }
}

// ---------------------------------------------------------------------------
// Launch. Two ws layouts chosen deterministically by ws_size:
//  big (>=64MiB): WT@0, Qb@8M, Kb@16M, Vb@24M, Qp@32M, Kp@40M, Vtp@48M, An@56M
//     cvt x3 -> fused proj (grid.z=3, 768 blocks) -> attn -> out
//  small:        WT@0, Xb/An@8M, Qp@16M, Kp@24M, Vtp@32M   (40 MiB)
//     (cvt -> proj) x3 reusing Xb -> attn -> out
// ---------------------------------------------------------------------------
extern "C" void kernel_launch(void* const* d_in, const int* in_sizes, int n_in,
                              void* d_out, int out_size, void* d_ws, size_t ws_size,
                              hipStream_t stream) {
    const float* queries = (const float*)d_in[0];
    const float* keys    = (const float*)d_in[1];
    const float* values  = (const float*)d_in[2];
    const float* Wq = (const float*)d_in[3];
    const float* bq = (const float*)d_in[4];
    const float* Wk = (const float*)d_in[5];
    const float* bk = (const float*)d_in[6];
    const float* Wv = (const float*)d_in[7];
    const float* bv = (const float*)d_in[8];
    const float* Wo = (const float*)d_in[9];
    const float* bo = (const float*)d_in[10];
    float* out = (float*)d_out;

    char* ws = (char*)d_ws;
    const size_t MB = 1024 * 1024;
    ushort_t* WT = (ushort_t*)(ws);
    dim3 tb(256);

    transpose_w<<<dim3(256, 4), tb, 0, stream>>>(Wq, Wk, Wv, Wo, WT);

    if (ws_size >= 64 * MB) {
        ushort_t* Qb  = (ushort_t*)(ws + 8 * MB);
        ushort_t* Kb  = (ushort_t*)(ws + 16 * MB);
        ushort_t* Vb  = (ushort_t*)(ws + 24 * MB);
        ushort_t* Qp  = (ushort_t*)(ws + 32 * MB);
        ushort_t* Kp  = (ushort_t*)(ws + 40 * MB);
        ushort_t* Vtp = (ushort_t*)(ws + 48 * MB);
        ushort_t* An  = (ushort_t*)(ws + 56 * MB);
        cvt_bf16<<<dim3(2048), tb, 0, stream>>>(queries, Qb);
        cvt_bf16<<<dim3(2048), tb, 0, stream>>>(keys, Kb);
        cvt_bf16<<<dim3(2048), tb, 0, stream>>>(values, Vb);
        gemm_bt<<<dim3(8, 32, 3), tb, 0, stream>>>(Qb, Kb, Vb, An, WT,
            bq, bk, bv, bo, Qp, Kp, Vtp, out, 0);
        attn64<<<dim3(32, 32), tb, 0, stream>>>(Qp, Kp, Vtp, An);
        gemm_bt<<<dim3(8, 32, 1), tb, 0, stream>>>(Qb, Kb, Vb, An, WT,
            bq, bk, bv, bo, Qp, Kp, Vtp, out, 3);
    } else {
        ushort_t* Xb  = (ushort_t*)(ws + 8 * MB);
        ushort_t* An  = (ushort_t*)(ws + 8 * MB);  // overlays Xb (dead by then)
        ushort_t* Qp  = (ushort_t*)(ws + 16 * MB);
        ushort_t* Kp  = (ushort_t*)(ws + 24 * MB);
        ushort_t* Vtp = (ushort_t*)(ws + 32 * MB);
        cvt_bf16<<<dim3(2048), tb, 0, stream>>>(queries, Xb);
        gemm_bt<<<dim3(8, 32, 1), tb, 0, stream>>>(Xb, Xb, Xb, An, WT,
            bq, bk, bv, bo, Qp, Kp, Vtp, out, 0);
        cvt_bf16<<<dim3(2048), tb, 0, stream>>>(keys, Xb);
        gemm_bt<<<dim3(8, 32, 1), tb, 0, stream>>>(Xb, Xb, Xb, An, WT,
            bq, bk, bv, bo, Qp, Kp, Vtp, out, 1);
        cvt_bf16<<<dim3(2048), tb, 0, stream>>>(values, Xb);
        gemm_bt<<<dim3(8, 32, 1), tb, 0, stream>>>(Xb, Xb, Xb, An, WT,
            bq, bk, bv, bo, Qp, Kp, Vtp, out, 2);
        attn64<<<dim3(32, 32), tb, 0, stream>>>(Qp, Kp, Vtp, An);
        gemm_bt<<<dim3(8, 32, 1), tb, 0, stream>>>(Xb, Xb, Xb, An, WT,
            bq, bk, bv, bo, Qp, Kp, Vtp, out, 3);
    }
}

// Round 7
// 237.311 us; speedup vs baseline: 1.4773x; 1.1098x over previous
//
#include <hip/hip_runtime.h>

typedef unsigned short ushort_t;
typedef unsigned int uint_t;
typedef __attribute__((ext_vector_type(8))) short short8;
typedef __attribute__((ext_vector_type(4))) float floatx4;

#define QSCALE 0.03187936f  // (1/sqrt(2048)) * log2(e): quirk scale + exp2 fold

__device__ __forceinline__ ushort_t f2bf(float f) {
    union { float f; uint_t u; } c; c.f = f;
    uint_t u = c.u;
    return (ushort_t)((u + 0x7fffu + ((u >> 16) & 1u)) >> 16);  // RNE
}
__device__ __forceinline__ floatx4 mfma16x32(short8 a, short8 b, floatx4 c) {
    return __builtin_amdgcn_mfma_f32_16x16x32_bf16(a, b, c, 0, 0, 0);
}
__device__ __forceinline__ floatx4 zero4() { floatx4 z = {0.f, 0.f, 0.f, 0.f}; return z; }

// Async 16B global->LDS. Per-lane lds ptr = base + lane*16B slot (HW uses
// lane0's ptr as wave base and strides lane*16 — matches our linear slots).
__device__ __forceinline__ void gload16(const ushort_t* g, ushort_t* l) {
    __builtin_amdgcn_global_load_lds(
        (const __attribute__((address_space(1))) void*)g,
        (__attribute__((address_space(3))) void*)l, 16, 0, 0);
}

// ---------------------------------------------------------------------------
// f32 -> bf16 convert (RNE), 8 elems/thread, up to 3 tensors of 4M elems.
// which = blockIdx.x>>11 selects tensor; launch grid 2048*n.
// ---------------------------------------------------------------------------
__global__ __launch_bounds__(256) void cvt_bf16(
    const float* __restrict__ s0, const float* __restrict__ s1,
    const float* __restrict__ s2, ushort_t* __restrict__ d0,
    ushort_t* __restrict__ d1, ushort_t* __restrict__ d2)
{
    const int which = blockIdx.x >> 11;
    const int blk = blockIdx.x & 2047;
    const float* src = (which == 0) ? s0 : (which == 1) ? s1 : s2;
    ushort_t* dst = (which == 0) ? d0 : (which == 1) ? d1 : d2;
    const int i = (blk * 256 + threadIdx.x) * 8;
    float4 f0 = *(const float4*)(src + i);
    float4 f1 = *(const float4*)(src + i + 4);
    __align__(16) ushort_t t[8];
    t[0] = f2bf(f0.x); t[1] = f2bf(f0.y); t[2] = f2bf(f0.z); t[3] = f2bf(f0.w);
    t[4] = f2bf(f1.x); t[5] = f2bf(f1.y); t[6] = f2bf(f1.z); t[7] = f2bf(f1.w);
    *(uint4*)(dst + i) = *(uint4*)t;
}

// ---------------------------------------------------------------------------
// Fused convert+transpose: W[k][j] (1024x1024 f32) -> WT[j][k] bf16.
// ---------------------------------------------------------------------------
__global__ __launch_bounds__(256) void transpose_w(
    const float* __restrict__ W0, const float* __restrict__ W1,
    const float* __restrict__ W2, const float* __restrict__ W3,
    ushort_t* __restrict__ WT)
{
    __shared__ ushort_t tile[64][65];
    const float* W = (blockIdx.y == 0) ? W0 : (blockIdx.y == 1) ? W1
                   : (blockIdx.y == 2) ? W2 : W3;
    ushort_t* dst = WT + (size_t)blockIdx.y * (1024 * 1024);
    const int t = threadIdx.x;
    const int r = t >> 2, p = t & 3;
    const int j0 = (blockIdx.x & 15) << 6, k0 = (blockIdx.x >> 4) << 6;

    const float* src = W + (size_t)(k0 + r) * 1024 + j0 + p * 16;
    float4 f0 = *(const float4*)(src);
    float4 f1 = *(const float4*)(src + 4);
    float4 f2 = *(const float4*)(src + 8);
    float4 f3 = *(const float4*)(src + 12);
    ushort_t* tr = &tile[r][p * 16];
    tr[0] = f2bf(f0.x); tr[1] = f2bf(f0.y); tr[2]  = f2bf(f0.z); tr[3]  = f2bf(f0.w);
    tr[4] = f2bf(f1.x); tr[5] = f2bf(f1.y); tr[6]  = f2bf(f1.z); tr[7]  = f2bf(f1.w);
    tr[8] = f2bf(f2.x); tr[9] = f2bf(f2.y); tr[10] = f2bf(f2.z); tr[11] = f2bf(f2.w);
    tr[12] = f2bf(f3.x); tr[13] = f2bf(f3.y); tr[14] = f2bf(f3.z); tr[15] = f2bf(f3.w);
    __syncthreads();
    __align__(16) ushort_t buf[16];
#pragma unroll
    for (int i = 0; i < 16; ++i) buf[i] = tile[p * 16 + i][r];
    ushort_t* o = dst + (size_t)(j0 + r) * 1024 + k0 + p * 16;
    *(uint4*)(o)     = *(uint4*)(buf);
    *(uint4*)(o + 8) = *(uint4*)(buf + 8);
}

// ---------------------------------------------------------------------------
// Projection GEMM: C[r][c] = sum_k A[r][k]*WT[c][k] + bias[c]. 4096x1024x1024.
// 128x128 tile, BK=32, global_load_lds staging, XOR-swizzled LDS chunks.
// mode = blockIdx.z + zbase: 0: Q -> [B,H,S,64] *QSCALE; 1: K -> [B,H,S,64];
// 2: V -> [B,H,64,S].
// ---------------------------------------------------------------------------
__global__ __launch_bounds__(256) void gemm_bt(
    const ushort_t* __restrict__ A0, const ushort_t* __restrict__ A1,
    const ushort_t* __restrict__ A2, const ushort_t* __restrict__ WT,
    const float* __restrict__ b0, const float* __restrict__ b1,
    const float* __restrict__ b2,
    ushort_t* __restrict__ Dq, ushort_t* __restrict__ Dk,
    ushort_t* __restrict__ Dv, int zbase)
{
    __shared__ __align__(16) ushort_t As[128 * 32];
    __shared__ __align__(16) ushort_t Bs[128 * 32];

    const int mode = blockIdx.z + zbase;
    const ushort_t* A = (mode == 0) ? A0 : (mode == 1) ? A1 : A2;
    const float* bias = (mode == 0) ? b0 : (mode == 1) ? b1 : b2;
    const ushort_t* Bt = WT + (size_t)mode * 1048576;

    const int tid = threadIdx.x;
    const int lane = tid & 63, wid = tid >> 6;
    const int quad = lane >> 4, l16 = lane & 15;
    const int wm = wid >> 1, wn = wid & 1;
    const int row0 = blockIdx.y << 7, col0 = blockIdx.x << 7;

    floatx4 acc[4][4];
#pragma unroll
    for (int i = 0; i < 4; ++i)
#pragma unroll
        for (int j = 0; j < 4; ++j) acc[i][j] = zero4();

    const int i0 = tid, i1 = 256 + tid;
    const int r0_ = i0 >> 2, c0_ = (i0 & 3) ^ (r0_ & 3);
    const int r1_ = i1 >> 2, c1_ = (i1 & 3) ^ (r1_ & 3);
    const ushort_t* gA0 = A  + (size_t)(row0 + r0_) * 1024 + c0_ * 8;
    const ushort_t* gA1 = A  + (size_t)(row0 + r1_) * 1024 + c1_ * 8;
    const ushort_t* gB0 = Bt + (size_t)(col0 + r0_) * 1024 + c0_ * 8;
    const ushort_t* gB1 = Bt + (size_t)(col0 + r1_) * 1024 + c1_ * 8;
    ushort_t* lA0 = As + i0 * 8;  ushort_t* lA1 = As + i1 * 8;
    ushort_t* lB0 = Bs + i0 * 8;  ushort_t* lB1 = Bs + i1 * 8;

    const int ra = wm * 64 + l16, rb = wn * 64 + l16;
    const int sa_off = (quad ^ (l16 & 3)) * 8;

    for (int k0 = 0; k0 < 1024; k0 += 32) {
        __syncthreads();
        gload16(gA0 + k0, lA0);
        gload16(gA1 + k0, lA1);
        gload16(gB0 + k0, lB0);
        gload16(gB1 + k0, lB1);
        __syncthreads();

        short8 af[4], bf[4];
#pragma unroll
        for (int i = 0; i < 4; ++i)
            af[i] = *(const short8*)(As + (ra + i * 16) * 32 + sa_off);
#pragma unroll
        for (int j = 0; j < 4; ++j)
            bf[j] = *(const short8*)(Bs + (rb + j * 16) * 32 + sa_off);
#pragma unroll
        for (int i = 0; i < 4; ++i)
#pragma unroll
            for (int j = 0; j < 4; ++j)
                acc[i][j] = mfma16x32(af[i], bf[j], acc[i][j]);
    }

    const float sc = (mode == 0) ? QSCALE : 1.f;
#pragma unroll
    for (int i = 0; i < 4; ++i) {
#pragma unroll
        for (int j = 0; j < 4; ++j) {
            const int c = col0 + wn * 64 + j * 16 + l16;
            const float bv = bias[c];
#pragma unroll
            for (int rr = 0; rr < 4; ++rr) {
                const int r = row0 + wm * 64 + i * 16 + quad * 4 + rr;
                const float v = (acc[i][j][rr] + bv) * sc;
                const int b = r >> 11, s = r & 2047, h = c >> 6, d = c & 63;
                if (mode <= 1) {
                    ushort_t* D = (mode == 0) ? Dq : Dk;
                    D[(((b * 16 + h) * 2048 + s) << 6) + d] = f2bf(v);
                } else {
                    Dv[(((b * 16 + h) * 64 + d) << 11) + s] = f2bf(v);
                }
            }
        }
    }
}

// ---------------------------------------------------------------------------
// Output GEMM: Dout[r][c] = sum_k A[r][k]*WoT[c][k] + bias[c], f32 out.
// 64x128 tile -> 512 blocks (2 blocks/CU) to hide staging-barrier drains.
// ---------------------------------------------------------------------------
__global__ __launch_bounds__(256) void gemm64(
    const ushort_t* __restrict__ A, const ushort_t* __restrict__ Bt,
    const float* __restrict__ bias, float* __restrict__ Dout)
{
    __shared__ __align__(16) ushort_t As[64 * 32];
    __shared__ __align__(16) ushort_t Bs[128 * 32];
    const int tid = threadIdx.x;
    const int lane = tid & 63, wid = tid >> 6;
    const int quad = lane >> 4, l16 = lane & 15;
    const int wm = wid >> 1, wn = wid & 1;
    const int row0 = blockIdx.y << 6, col0 = blockIdx.x << 7;

    floatx4 acc[2][4];
#pragma unroll
    for (int i = 0; i < 2; ++i)
#pragma unroll
        for (int j = 0; j < 4; ++j) acc[i][j] = zero4();

    const int rA = tid >> 2, cA = (tid & 3) ^ (rA & 3);
    const ushort_t* gA = A + (size_t)(row0 + rA) * 1024 + cA * 8;
    ushort_t* lA = As + tid * 8;
    const int i0 = tid, i1 = 256 + tid;
    const int rB0 = i0 >> 2, cB0 = (i0 & 3) ^ (rB0 & 3);
    const int rB1 = i1 >> 2, cB1 = (i1 & 3) ^ (rB1 & 3);
    const ushort_t* gB0 = Bt + (size_t)(col0 + rB0) * 1024 + cB0 * 8;
    const ushort_t* gB1 = Bt + (size_t)(col0 + rB1) * 1024 + cB1 * 8;
    ushort_t* lB0 = Bs + i0 * 8;  ushort_t* lB1 = Bs + i1 * 8;

    const int sa_off = (quad ^ (l16 & 3)) * 8;

    for (int k0 = 0; k0 < 1024; k0 += 32) {
        __syncthreads();
        gload16(gA + k0, lA);
        gload16(gB0 + k0, lB0);
        gload16(gB1 + k0, lB1);
        __syncthreads();

        short8 af[2], bf[4];
#pragma unroll
        for (int i = 0; i < 2; ++i)
            af[i] = *(const short8*)(As + (wm * 32 + i * 16 + l16) * 32 + sa_off);
#pragma unroll
        for (int j = 0; j < 4; ++j)
            bf[j] = *(const short8*)(Bs + (wn * 64 + j * 16 + l16) * 32 + sa_off);
#pragma unroll
        for (int i = 0; i < 2; ++i)
#pragma unroll
            for (int j = 0; j < 4; ++j)
                acc[i][j] = mfma16x32(af[i], bf[j], acc[i][j]);
    }

#pragma unroll
    for (int i = 0; i < 2; ++i)
#pragma unroll
        for (int j = 0; j < 4; ++j) {
            const int c = col0 + wn * 64 + j * 16 + l16;
            const float bv = bias[c];
#pragma unroll
            for (int rr = 0; rr < 4; ++rr) {
                const int r = row0 + wm * 32 + i * 16 + quad * 4 + rr;
                Dout[(size_t)r * 1024 + c] = acc[i][j][rr] + bv;
            }
        }
}

// ---------------------------------------------------------------------------
// Attention via S^T trick, full-K PV. Per block: (head bh, 64 q-rows).
// S^T = K·Q^T -> lane (l16,quad) holds P[qrow=l16][kcol=g*16+quad*4+r].
// PV uses K=32 MFMA with the SEMANTIC k-slot mapping: slots j=0..3 -> kcols
// 4q+j of g-block 2G, slots j=4..7 -> kcols 4q+(j-4) of g-block 2G+1 —
// identical on A (packed P, no zeros, no shuffles) and B (two b64 V reads).
// Fixed-shift softmax: p=exp2(min(s,80)) (scale+log2e folded into Q proj),
// p truncated to bf16, denominator summed over truncated values.
// ---------------------------------------------------------------------------
__global__ __launch_bounds__(256, 4) void attn64(
    const ushort_t* __restrict__ Q, const ushort_t* __restrict__ K,
    const ushort_t* __restrict__ Vt, ushort_t* __restrict__ Out)
{
    __shared__ __align__(16) ushort_t Ks[64 * 64];  // [kcol][d], swizzled chunks
    __shared__ __align__(16) ushort_t Vs[64 * 64];  // [d][kcol], swizzled chunks

    const int tid = threadIdx.x;
    const int lane = tid & 63, wid = tid >> 6;
    const int quad = lane >> 4, l16 = lane & 15;
    const int bh = blockIdx.y;
    const int q0 = blockIdx.x << 6;

    const ushort_t* Qh = Q + (size_t)bh * (2048 * 64);
    const ushort_t* Kh = K + (size_t)bh * (2048 * 64);
    const ushort_t* Vh = Vt + (size_t)bh * (64 * 2048);

    const int qr = q0 + wid * 16 + l16;
    const short8 qf0 = *(const short8*)(Qh + (size_t)qr * 64 + quad * 8);
    const short8 qf1 = *(const short8*)(Qh + (size_t)qr * 64 + 32 + quad * 8);

    float l_st = 0.f;
    floatx4 o_acc[4];
#pragma unroll
    for (int d = 0; d < 4; ++d) o_acc[d] = zero4();

    const int i0 = tid, i1 = 256 + tid;
    const int kr0 = i0 >> 3, kc0 = (i0 & 7) ^ (kr0 & 7);
    const int kr1 = i1 >> 3, kc1 = (i1 & 7) ^ (kr1 & 7);
    const ushort_t* gK0 = Kh + (size_t)kr0 * 64 + kc0 * 8;
    const ushort_t* gK1 = Kh + (size_t)kr1 * 64 + kc1 * 8;
    const ushort_t* gV0 = Vh + (size_t)kr0 * 2048 + kc0 * 8;
    const ushort_t* gV1 = Vh + (size_t)kr1 * 2048 + kc1 * 8;
    ushort_t* lK0 = Ks + i0 * 8;  ushort_t* lK1 = Ks + i1 * 8;
    ushort_t* lV0 = Vs + i0 * 8;  ushort_t* lV1 = Vs + i1 * 8;

    const int l7 = l16 & 7;
    const int q2 = quad >> 1, q1 = (quad & 1) * 4;

    for (int kt = 0; kt < 2048; kt += 64) {
        __syncthreads();
        gload16(gK0 + (size_t)kt * 64, lK0);
        gload16(gK1 + (size_t)kt * 64, lK1);
        gload16(gV0 + kt, lV0);
        gload16(gV1 + kt, lV1);
        __syncthreads();

        // S^T tiles: A = K-frag (m=kcol), B = Q-frag (n=qrow)
        floatx4 sa[4];
#pragma unroll
        for (int g = 0; g < 4; ++g) {
            const int row = g * 16 + l16;  // kcol
            const short8 kf0 = *(const short8*)(Ks + row * 64 + ((quad ^ l7) * 8));
            const short8 kf1 = *(const short8*)(Ks + row * 64 + (((quad + 4) ^ l7) * 8));
            sa[g] = mfma16x32(kf0, qf0, zero4());
            sa[g] = mfma16x32(kf1, qf1, sa[g]);
        }

        // softmax + pack two g-blocks per K=32 PV MFMA (no padding waste)
#pragma unroll
        for (int G = 0; G < 2; ++G) {
            uint_t ub[8];
#pragma unroll
            for (int t = 0; t < 8; ++t) {
                const int g = G * 2 + (t >> 2), r = t & 3;
                const float e = __builtin_amdgcn_exp2f(fminf(sa[g][r], 80.f));
                const uint_t u = __float_as_uint(e) & 0xffff0000u;
                l_st += __uint_as_float(u);   // sum the TRUNCATED value
                ub[t] = u;
            }
            union { uint_t u[4]; short8 s; } pc;
            pc.u[0] = (ub[0] >> 16) | ub[1];
            pc.u[1] = (ub[2] >> 16) | ub[3];
            pc.u[2] = (ub[4] >> 16) | ub[5];
            pc.u[3] = (ub[6] >> 16) | ub[7];
            const short8 pf = pc.s;

            const int ch0 = ((4 * G + q2) ^ l7) * 8;
            const int ch1 = ((4 * G + 2 + q2) ^ l7) * 8;
#pragma unroll
            for (int db = 0; db < 4; ++db) {
                const int vbase = (db * 16 + l16) * 64 + q1;
                const uint2 v0 = *(const uint2*)(Vs + vbase + ch0);
                const uint2 v1 = *(const uint2*)(Vs + vbase + ch1);
                union { uint_t u[4]; short8 s; } vc;
                vc.u[0] = v0.x; vc.u[1] = v0.y; vc.u[2] = v1.x; vc.u[3] = v1.y;
                o_acc[db] = mfma16x32(pf, vc.s, o_acc[db]);
            }
        }
    }

    // denominator: sum across the 4 quads sharing qrow=l16
    l_st += __shfl_xor(l_st, 16);
    l_st += __shfl_xor(l_st, 32);

    const int b = bh >> 4, h = bh & 15;
    const int s0 = q0 + wid * 16 + quad * 4;
#pragma unroll
    for (int r = 0; r < 4; ++r) {
        const float lr = __shfl(l_st, quad * 4 + r);  // l of qrow quad*4+r
        const float inv = 1.f / lr;
#pragma unroll
        for (int db = 0; db < 4; ++db) {
            const float v = o_acc[db][r] * inv;
            Out[(size_t)(b * 2048 + s0 + r) * 1024 + h * 64 + db * 16 + l16] = f2bf(v);
        }
    }
}

// ---------------------------------------------------------------------------
// Launch.
//  big (>=64MiB): WT@0 Qb@8M Kb@16M Vb@24M Qp@32M Kp@40M Vtp@48M An@56M
//     tp -> cvt3 -> gemm z=3 -> attn -> gemm64
//  small (40MiB): WT@0 buf1@8M buf2@16M Qp@24M Kp@32M
//     tp -> cvt(Q,K) -> gemm z=2 (QK, 2/CU) -> cvt(V->buf1)
//        -> gemm z=1 (V: buf1 -> Vtp=buf2) -> attn(->An=buf1) -> gemm64
// ---------------------------------------------------------------------------
extern "C" void kernel_launch(void* const* d_in, const int* in_sizes, int n_in,
                              void* d_out, int out_size, void* d_ws, size_t ws_size,
                              hipStream_t stream) {
    const float* queries = (const float*)d_in[0];
    const float* keys    = (const float*)d_in[1];
    const float* values  = (const float*)d_in[2];
    const float* Wq = (const float*)d_in[3];
    const float* bq = (const float*)d_in[4];
    const float* Wk = (const float*)d_in[5];
    const float* bk = (const float*)d_in[6];
    const float* Wv = (const float*)d_in[7];
    const float* bv = (const float*)d_in[8];
    const float* Wo = (const float*)d_in[9];
    const float* bo = (const float*)d_in[10];
    float* out = (float*)d_out;

    char* ws = (char*)d_ws;
    const size_t MB = 1024 * 1024;
    ushort_t* WT = (ushort_t*)(ws);
    const ushort_t* WoT = WT + 3 * 1048576;
    dim3 tb(256);

    transpose_w<<<dim3(256, 4), tb, 0, stream>>>(Wq, Wk, Wv, Wo, WT);

    if (ws_size >= 64 * MB) {
        ushort_t* Qb  = (ushort_t*)(ws + 8 * MB);
        ushort_t* Kb  = (ushort_t*)(ws + 16 * MB);
        ushort_t* Vb  = (ushort_t*)(ws + 24 * MB);
        ushort_t* Qp  = (ushort_t*)(ws + 32 * MB);
        ushort_t* Kp  = (ushort_t*)(ws + 40 * MB);
        ushort_t* Vtp = (ushort_t*)(ws + 48 * MB);
        ushort_t* An  = (ushort_t*)(ws + 56 * MB);
        cvt_bf16<<<dim3(6144), tb, 0, stream>>>(queries, keys, values, Qb, Kb, Vb);
        gemm_bt<<<dim3(8, 32, 3), tb, 0, stream>>>(Qb, Kb, Vb, WT,
            bq, bk, bv, Qp, Kp, Vtp, 0);
        attn64<<<dim3(32, 32), tb, 0, stream>>>(Qp, Kp, Vtp, An);
        gemm64<<<dim3(8, 64), tb, 0, stream>>>(An, WoT, bo, out);
    } else {
        ushort_t* buf1 = (ushort_t*)(ws + 8 * MB);
        ushort_t* buf2 = (ushort_t*)(ws + 16 * MB);
        ushort_t* Qp   = (ushort_t*)(ws + 24 * MB);
        ushort_t* Kp   = (ushort_t*)(ws + 32 * MB);
        cvt_bf16<<<dim3(4096), tb, 0, stream>>>(queries, keys, keys, buf1, buf2, buf2);
        gemm_bt<<<dim3(8, 32, 2), tb, 0, stream>>>(buf1, buf2, buf2, WT,
            bq, bk, bk, Qp, Kp, Kp, 0);
        cvt_bf16<<<dim3(2048), tb, 0, stream>>>(values, values, values, buf1, buf1, buf1);
        gemm_bt<<<dim3(8, 32, 1), tb, 0, stream>>>(buf1, buf1, buf1, WT,
            bv, bv, bv, buf2, buf2, buf2, 2);   // mode 2: V -> Vtp=buf2
        attn64<<<dim3(32, 32), tb, 0, stream>>>(Qp, Kp, buf2, buf1);
        gemm64<<<dim3(8, 64), tb, 0, stream>>>(buf1, WoT, bo, out);
    }
}